// Round 6
// baseline (219.835 us; speedup 1.0000x reference)
//
#include <hip/hip_runtime.h>
#include <hip/hip_bf16.h>
#include <cstddef>
#include <cstdint>

// Problem constants
#define BATCH 2
#define SEQ   1024
#define DMODEL 1024
#define NHEADS 16
#define DHEAD 64
#define E3D   3072
#define NCHUNK 64   // chunks along S
#define CHUNK 16    // positions per chunk

// beta (normalized), nonzero only for p=1..5 (T1..T5)
#define BETA1 0.45736626f
#define BETA2 0.26218724f
#define BETA3 0.15594524f
#define BETA4 0.08693904f
#define BETA5 0.03756222f

#define RSCALE 2048.f
#define RINV   4.8828125e-4f   // 1/2048

typedef __attribute__((ext_vector_type(8))) _Float16 half8;
typedef __attribute__((ext_vector_type(16))) float floatx16;

__device__ __forceinline__ void cp16(const void* g, void* l) {
    __builtin_amdgcn_global_load_lds(
        (const __attribute__((address_space(1))) void*)(uintptr_t)g,
        (__attribute__((address_space(3))) void*)(uintptr_t)l,
        16, 0, 0);
}

// fp16 2-level split: x ~= h + m/2048 (residual pre-scaled so it stays normal)
__device__ __forceinline__ void split2(float x, unsigned short* H, unsigned short* M) {
    _Float16 h = (_Float16)x;
    float r = (x - (float)h) * RSCALE;
    _Float16 m = (_Float16)r;
    *H = __builtin_bit_cast(unsigned short, h);
    *M = __builtin_bit_cast(unsigned short, m);
}

__device__ __forceinline__ void split2x4(const float4 v,
                                         unsigned short* h, unsigned short* m,
                                         size_t i4) {
    float vv[4] = {v.x, v.y, v.z, v.w};
    unsigned short hh[4], mm[4];
#pragma unroll
    for (int j = 0; j < 4; j++) split2(vv[j], &hh[j], &mm[j]);
    ((ushort4*)h)[i4] = make_ushort4(hh[0], hh[1], hh[2], hh[3]);
    ((ushort4*)m)[i4] = make_ushort4(mm[0], mm[1], mm[2], mm[3]);
}

__device__ __forceinline__ void cheb5(float x, float T[6]) {
    T[0] = 1.f; T[1] = x;
    float tx2 = 2.f * x;
    T[2] = tx2 * T[1] - T[0];
    T[3] = tx2 * T[2] - T[1];
    T[4] = tx2 * T[3] - T[2];
    T[5] = tx2 * T[4] - T[3];
}

__device__ __forceinline__ float clampx(float v) {
    return fminf(fmaxf(v * 0.125f, -1.f + 1e-6f), 1.f - 1e-6f);
}

__device__ __forceinline__ float wave_sum(float x) {
#pragma unroll
    for (int m = 32; m >= 1; m >>= 1) x += __shfl_xor(x, m, 64);
    return x;
}

// ---------------------------------------------------------------------------
// Fused split of x (2048 blocks) and Win (3072 blocks): fp16 2-level.
// ---------------------------------------------------------------------------
__global__ __launch_bounds__(256) void k_splitall(
    const float* __restrict__ x, const float* __restrict__ Win,
    unsigned short* __restrict__ Xh, unsigned short* __restrict__ Xm,
    unsigned short* __restrict__ Wh, unsigned short* __restrict__ Wm)
{
    const float* in; unsigned short *h, *m; int i;
    if (blockIdx.x < 2048) {
        in = x; h = Xh; m = Xm;
        i = blockIdx.x * 256 + threadIdx.x;
    } else {
        in = Win; h = Wh; m = Wm;
        i = (blockIdx.x - 2048) * 256 + threadIdx.x;
    }
    split2x4(((const float4*)in)[i], h, m, i);
}

// ---------------------------------------------------------------------------
// fp16 scaled-residual MFMA GEMM (32x32x16): C[m,n] = sum_k A[m,k]*B[n,k].
// A = Ah + Am/2048, B likewise: acc1 += Ah*Bh; acc2 += Ah*Bm + Am*Bh;
// C = acc1 + acc2/2048.
// Block tile 64 x TN, BK=32, 256 threads = 4 waves (2x2); wave = 32 rows x
// (TN/2) cols = NT=TN/64 tiles of 32x32 (dual accumulators).
//
// FRAGMENT-MAJOR LDS LAYOUT (round-6): chunk (row r, 8-elem k-seg s) of a
// split tile lives at byte (r>>5)*2048 + (s>>1)*1024 + (s&1)*512 + (r&31)*16.
// => every MFMA fragment read is [wave-uniform base + lane*16] — a contiguous
// 1 KB block, bank-conflict-free by construction. cp16's LDS dest is likewise
// uniform+lane*16; the per-lane GLOBAL source address absorbs the layout
// permutation: staging call (group g, pair p): lane fetches
// row g*32+(lane&31), seg 2p+(lane>>5).
// MFMA mapping (32x32x16 f16): A m=lane&31, k=(lane>>5)*8+j; kk-th call of a
// BK=32 slab uses segs s=2*kk+(lane>>5): (s>>1)=kk, (s&1)=lane>>5  ✓.
// C/D: col=lane&31, row=(reg&3)+8*(reg>>2)+4*(lane>>5).
// ---------------------------------------------------------------------------
template<int TN>
__device__ __forceinline__ void gemm_body(
    const unsigned short* __restrict__ Ah, const unsigned short* __restrict__ Am,
    const unsigned short* __restrict__ Bh, const unsigned short* __restrict__ Bm,
    float* __restrict__ C, int M, int N, int K)
{
    constexpr int NT     = TN / 64;      // 32x32 N-tiles per wave
    constexpr int ABYTES = 4096;         // one A split tile (64 x 32 x 2 B)
    constexpr int BBYTES = TN * 64;      // one B split tile
    constexpr int NC     = 8 + TN / 8;   // staging calls per K-iter (1 KB each)
    constexpr int PW     = NC / 4;       // calls per wave
    __shared__ unsigned char lds[2 * ABYTES + 2 * BBYTES];

    const int tid  = threadIdx.x;
    const int w    = tid >> 6;
    const int lane = tid & 63;
    const int m0 = blockIdx.y * 64;
    const int n0 = blockIdx.x * TN;

    // ---- staging call table (computed once; only k0 varies in the loop) ----
    const int lrow = lane & 31;   // row within a 32-row group
    const int lseg = lane >> 5;   // position within a seg pair
    const unsigned short* src[PW];
    size_t goff[PW];
    int loff[PW];
#pragma unroll
    for (int j = 0; j < PW; j++) {
        const int id = w * PW + j;
        if (id < 8) {                       // A: 2 splits x 2 groups x 2 pairs
            const int split = id >> 2, rem = id & 3, gg = rem >> 1, p = rem & 1;
            src[j]  = split ? Am : Ah;
            goff[j] = (size_t)(m0 + gg * 32 + lrow) * K + (2 * p + lseg) * 8;
            loff[j] = split * ABYTES + gg * 2048 + p * 1024;
        } else {                            // B: 2 splits x (TN/32) groups x 2
            const int bid = id - 8;
            const int split = bid / (TN / 16), rem = bid % (TN / 16);
            const int gg = rem >> 1, p = rem & 1;
            src[j]  = split ? Bm : Bh;
            goff[j] = (size_t)(n0 + gg * 32 + lrow) * K + (2 * p + lseg) * 8;
            loff[j] = 2 * ABYTES + split * BBYTES + gg * 2048 + p * 1024;
        }
    }

    // ---- fragment read bases (contiguous, conflict-free) ----
    const int wm = w & 1, wn = w >> 1;
    const int abase  = wm * 2048 + lane * 16;                    // +kk*1024 (+ABYTES for mid)
    const int bbase0 = 2 * ABYTES + wn * NT * 2048 + lane * 16;  // +nt*2048 +kk*1024 (+BBYTES)

    floatx16 acc1[NT] = {};
    floatx16 acc2[NT] = {};

    for (int k0 = 0; k0 < K; k0 += 32) {
        __syncthreads();
#pragma unroll
        for (int j = 0; j < PW; j++)
            cp16(src[j] + goff[j] + k0, &lds[loff[j]]);
        __syncthreads();

#pragma unroll
        for (int kk = 0; kk < 2; kk++) {
            half8 fah = *(const half8*)&lds[abase + kk * 1024];
            half8 fam = *(const half8*)&lds[ABYTES + abase + kk * 1024];
            half8 fbh[NT], fbm[NT];
#pragma unroll
            for (int nt = 0; nt < NT; nt++) {
                fbh[nt] = *(const half8*)&lds[bbase0 + nt * 2048 + kk * 1024];
                fbm[nt] = *(const half8*)&lds[bbase0 + BBYTES + nt * 2048 + kk * 1024];
            }
#pragma unroll
            for (int nt = 0; nt < NT; nt++) {
                acc1[nt] = __builtin_amdgcn_mfma_f32_32x32x16_f16(fah, fbh[nt], acc1[nt], 0, 0, 0);
                acc2[nt] = __builtin_amdgcn_mfma_f32_32x32x16_f16(fah, fbm[nt], acc2[nt], 0, 0, 0);
                acc2[nt] = __builtin_amdgcn_mfma_f32_32x32x16_f16(fam, fbh[nt], acc2[nt], 0, 0, 0);
            }
        }
    }

    // epilogue: col=lane&31, row=(reg&3)+8*(reg>>2)+4*(lane>>5)
    const int l32 = lane & 31, q32 = lane >> 5;
    const int r0 = m0 + wm * 32 + q32 * 4;
#pragma unroll
    for (int nt = 0; nt < NT; nt++) {
        const int c0 = n0 + wn * (TN / 2) + nt * 32 + l32;
#pragma unroll
        for (int reg = 0; reg < 16; reg++) {
            const int row = r0 + (reg & 3) + 8 * (reg >> 2);
            C[(size_t)row * N + c0] = acc1[nt][reg] + acc2[nt][reg] * RINV;
        }
    }
}

__global__ __launch_bounds__(256, 3) void gemm1(
    const unsigned short* __restrict__ Ah, const unsigned short* __restrict__ Am,
    const unsigned short* __restrict__ Bh, const unsigned short* __restrict__ Bm,
    float* __restrict__ C, int M, int N, int K)
{
    gemm_body<128>(Ah, Am, Bh, Bm, C, M, N, K);
}

__global__ __launch_bounds__(256, 3) void gemm2(
    const unsigned short* __restrict__ Ah, const unsigned short* __restrict__ Am,
    const unsigned short* __restrict__ Bh, const unsigned short* __restrict__ Bm,
    float* __restrict__ C, int M, int N, int K)
{
    gemm_body<64>(Ah, Am, Bh, Bm, C, M, N, K);
}

// ---------------------------------------------------------------------------
// Attention. qkv layout: [b*S+s][3072], q at h*64+d, k at +1024, v at +2048
// Fused mid kernel: [0,1024) Wout split | [1024,9216) per-position sums |
// [9216,9728) kv chunk totals.
// ---------------------------------------------------------------------------
__global__ __launch_bounds__(256) void k_mid(
    const float* __restrict__ Wout,
    unsigned short* __restrict__ Wouth, unsigned short* __restrict__ Woutm,
    const float* __restrict__ qkv,
    float* __restrict__ SQB, float* __restrict__ SK, float* __restrict__ KVC)
{
    const int blk = blockIdx.x;
    if (blk < 1024) {
        int i = blk * 256 + threadIdx.x;
        split2x4(((const float4*)Wout)[i], Wouth, Woutm, i);
        return;
    }
    if (blk < 9216) {
        const int lane = threadIdx.x & 63;
        const int pos  = (blk - 1024) * 4 + (threadIdx.x >> 6);
        const int bh = pos >> 10, s = pos & 1023;
        const int b = bh >> 4, h = bh & 15;
        const float* base = qkv + (size_t)(b * SEQ + s) * E3D + h * DHEAD + lane;
        float xq = clampx(base[0]);
        float xk = clampx(base[1024]);
        float Tq[6], Tk[6];
        cheb5(xq, Tq); cheb5(xk, Tk);
        const float BETA[5] = {BETA1, BETA2, BETA3, BETA4, BETA5};
#pragma unroll
        for (int p = 1; p <= 5; p++) {
            float sq = wave_sum(Tq[p]);
            float sk = wave_sum(Tk[p]);
            if (lane == 0) {
                SQB[(size_t)pos * 5 + p - 1] = sq * BETA[p - 1];
                SK[(size_t)pos * 5 + p - 1]  = sk;
            }
        }
        return;
    }
    {
        const int lane = threadIdx.x & 63;
        const int cid = (blk - 9216) * 4 + (threadIdx.x >> 6);
        const int bh = cid >> 6, chunk = cid & 63;
        const int b = bh >> 4, h = bh & 15;
        const float* kb = qkv + (size_t)(b * SEQ + chunk * CHUNK) * E3D + 1024 + h * DHEAD + lane;
        float kv[5] = {0.f, 0.f, 0.f, 0.f, 0.f};
#pragma unroll
        for (int i = 0; i < CHUNK; i++) {
            const float* row = kb + (size_t)i * E3D;
            float xk = clampx(row[0]);
            float v = row[1024];
            float T[6]; cheb5(xk, T);
#pragma unroll
            for (int p = 1; p <= 5; p++) kv[p - 1] += T[p] * v;
        }
#pragma unroll
        for (int p = 0; p < 5; p++) KVC[((size_t)cid * 5 + p) * 64 + lane] = kv[p];
    }
}

// Fused prefixes: (A) exclusive prefix over chunks of KVC in place (register
// preload -> independent loads); (B) SK chunk sums + exclusive prefix -> SKP.
__global__ __launch_bounds__(320) void k_prefix(float* __restrict__ KVC,
                                                const float* __restrict__ SK,
                                                float* __restrict__ SKP)
{
    __shared__ float csum[NCHUNK * 5];
    const int bh = blockIdx.x;
    const int t = threadIdx.x;   // 0..319, component = p*64+d
    float v[NCHUNK];
    const size_t base = (size_t)bh * NCHUNK * 320 + t;
#pragma unroll
    for (int c = 0; c < NCHUNK; c++) v[c] = KVC[base + (size_t)c * 320];
    float run = 0.f;
#pragma unroll
    for (int c = 0; c < NCHUNK; c++) {
        KVC[base + (size_t)c * 320] = run;
        run += v[c];
    }
    {
        const int chunk = t / 5, p = t % 5;
        const float* sb = SK + ((size_t)bh * SEQ + chunk * CHUNK) * 5 + p;
        float s = 0.f;
#pragma unroll
        for (int i = 0; i < CHUNK; i++) s += sb[i * 5];
        csum[chunk * 5 + p] = s;
    }
    __syncthreads();
    if (t < 5) {
        float run2 = 0.f;
        for (int c = 0; c < NCHUNK; c++) {
            SKP[((size_t)bh * NCHUNK + c) * 5 + t] = run2;
            run2 += csum[c * 5 + t];
        }
    }
}

// Fused den + output. One wave per chunk (4 waves/block). Lane = d.
// Writes out_h directly as fp16 2-level split (GEMM2 A operand).
__global__ __launch_bounds__(256) void k_out(const float* __restrict__ qkv,
                                             const float* __restrict__ KVC,
                                             const float* __restrict__ SK,
                                             const float* __restrict__ SKP,
                                             const float* __restrict__ SQB,
                                             unsigned short* __restrict__ OH,
                                             unsigned short* __restrict__ OM)
{
    const int lane = threadIdx.x & 63;
    const int cid = blockIdx.x * 4 + (threadIdx.x >> 6);
    const int bh = cid >> 6, chunk = cid & 63;
    const int b = bh >> 4, h = bh & 15;
    const float BETA[5] = {BETA1, BETA2, BETA3, BETA4, BETA5};

    const int li = lane & 15;
    const int pos = bh * SEQ + chunk * CHUNK + li;
    float den_r = 0.f;
#pragma unroll
    for (int p = 0; p < 5; p++) {
        float v = SK[(size_t)pos * 5 + p];
#pragma unroll
        for (int off = 1; off < 16; off <<= 1) {
            float n = __shfl_up(v, off, 64);
            if (li >= off) v += n;
        }
        den_r += SQB[(size_t)pos * 5 + p] * (SKP[((size_t)bh * NCHUNK + chunk) * 5 + p] + v);
    }

    float kv[5];
#pragma unroll
    for (int p = 0; p < 5; p++) kv[p] = KVC[((size_t)cid * 5 + p) * 64 + lane];

    const float* qb = qkv + (size_t)(b * SEQ + chunk * CHUNK) * E3D + h * DHEAD + lane;
    size_t obase = (size_t)(b * SEQ + chunk * CHUNK) * DMODEL + h * DHEAD + lane;
#pragma unroll
    for (int i = 0; i < CHUNK; i++) {
        const float* row = qb + (size_t)i * E3D;
        float xq = clampx(row[0]);
        float xk = clampx(row[1024]);
        float v = row[2048];
        float Tk_[6]; cheb5(xk, Tk_);
#pragma unroll
        for (int p = 1; p <= 5; p++) kv[p - 1] += Tk_[p] * v;
        float Tq_[6]; cheb5(xq, Tq_);
        float num = 0.f;
#pragma unroll
        for (int p = 1; p <= 5; p++) num += BETA[p - 1] * Tq_[p] * kv[p - 1];
        float d = __shfl(den_r, i, 64);
        float val = num / (d + 1e-7f);
        unsigned short hh, mm;
        split2(val, &hh, &mm);
        size_t oi = obase + (size_t)i * DMODEL;
        OH[oi] = hh; OM[oi] = mm;
    }
}

// ---------------------------------------------------------------------------

extern "C" void kernel_launch(void* const* d_in, const int* in_sizes, int n_in,
                              void* d_out, int out_size, void* d_ws, size_t ws_size,
                              hipStream_t stream)
{
    const float* x    = (const float*)d_in[0];  // (2,1024,1024)
    const float* Win  = (const float*)d_in[1];  // (3072,1024)
    const float* Wout = (const float*)d_in[2];  // (1024,1024)
    float* out = (float*)d_out;                 // (2,1024,1024)
    char* ws = (char*)d_ws;

    // workspace layout (byte offsets)
    float* QKV = (float*)(ws + 0);                              // 25,165,824 B
    unsigned short* Xh   = (unsigned short*)(ws + 25165824);    //  4,194,304 each
    unsigned short* Xm   = (unsigned short*)(ws + 29360128);
    unsigned short* Winh = (unsigned short*)(ws + 33554432);    //  6,291,456 each
    unsigned short* Winm = (unsigned short*)(ws + 39845888);    // end 46,137,344
    // After GEMM1, X/Win splits die -> reuse regions:
    float* SQB = (float*)(ws + 25165824);   // 655,360
    float* SK  = (float*)(ws + 25821184);   // 655,360
    float* SKP = (float*)(ws + 26476544);   //  40,960
    float* KVC = (float*)(ws + 26517504);   // 2,621,440 (end 29,138,944)
    unsigned short* OHh   = (unsigned short*)(ws + 33554432);   // 4,194,304 each
    unsigned short* OHm   = (unsigned short*)(ws + 37748736);
    unsigned short* Wouth = (unsigned short*)(ws + 41943040);   // 2,097,152 each
    unsigned short* Woutm = (unsigned short*)(ws + 44040192);   // end 46,137,344

    // split x + Win (one launch)
    k_splitall<<<5120, 256, 0, stream>>>(x, Win, Xh, Xm, Winh, Winm);

    // 1) QKV projection (M=2048, N=3072, K=1024): 64x128 tiles -> 768 blocks (3/CU)
    gemm1<<<dim3(24, 32), 256, 0, stream>>>(Xh, Xm, Winh, Winm,
                                            QKV, BATCH * SEQ, E3D, DMODEL);

    // 2) Wout split + per-position sums + kv chunk totals (one launch)
    k_mid<<<9728, 256, 0, stream>>>(Wout, Wouth, Woutm, QKV, SQB, SK, KVC);

    // 3) prefixes
    k_prefix<<<BATCH * NHEADS, 320, 0, stream>>>(KVC, SK, SKP);

    // 4) den + output (writes out_h as fp16 split)
    k_out<<<512, 256, 0, stream>>>(QKV, KVC, SK, SKP, SQB, OHh, OHm);

    // 5) output projection (M=2048, N=1024, K=1024): 64x64 tiles -> 512 blocks (2/CU)
    gemm2<<<dim3(16, 32), 256, 0, stream>>>(OHh, OHm, Wouth, Woutm,
                                            out, BATCH * SEQ, DMODEL, DMODEL);
}

// Round 7
// 168.658 us; speedup vs baseline: 1.3034x; 1.3034x over previous
//
#include <hip/hip_runtime.h>
#include <hip/hip_bf16.h>
#include <cstddef>
#include <cstdint>

// Problem constants
#define BATCH 2
#define SEQ   1024
#define DMODEL 1024
#define NHEADS 16
#define DHEAD 64
#define E3D   3072
#define NCHUNK 64   // chunks along S
#define CHUNK 16    // positions per chunk

// beta (normalized), nonzero only for p=1..5 (T1..T5)
#define BETA1 0.45736626f
#define BETA2 0.26218724f
#define BETA3 0.15594524f
#define BETA4 0.08693904f
#define BETA5 0.03756222f

#define RSCALE 2048.f
#define RINV   4.8828125e-4f   // 1/2048

typedef __attribute__((ext_vector_type(8))) _Float16 half8;
typedef __attribute__((ext_vector_type(4))) float floatx4;

__device__ __forceinline__ void cp16(const void* g, void* l) {
    __builtin_amdgcn_global_load_lds(
        (const __attribute__((address_space(1))) void*)(uintptr_t)g,
        (__attribute__((address_space(3))) void*)(uintptr_t)l,
        16, 0, 0);
}

// fp16 2-level split: x ~= h + m/2048 (residual pre-scaled so it stays normal)
__device__ __forceinline__ void split2(float x, unsigned short* H, unsigned short* M) {
    _Float16 h = (_Float16)x;
    float r = (x - (float)h) * RSCALE;
    _Float16 m = (_Float16)r;
    *H = __builtin_bit_cast(unsigned short, h);
    *M = __builtin_bit_cast(unsigned short, m);
}

__device__ __forceinline__ void split2x4(const float4 v,
                                         unsigned short* h, unsigned short* m,
                                         size_t i4) {
    float vv[4] = {v.x, v.y, v.z, v.w};
    unsigned short hh[4], mm[4];
#pragma unroll
    for (int j = 0; j < 4; j++) split2(vv[j], &hh[j], &mm[j]);
    ((ushort4*)h)[i4] = make_ushort4(hh[0], hh[1], hh[2], hh[3]);
    ((ushort4*)m)[i4] = make_ushort4(mm[0], mm[1], mm[2], mm[3]);
}

__device__ __forceinline__ void cheb5(float x, float T[6]) {
    T[0] = 1.f; T[1] = x;
    float tx2 = 2.f * x;
    T[2] = tx2 * T[1] - T[0];
    T[3] = tx2 * T[2] - T[1];
    T[4] = tx2 * T[3] - T[2];
    T[5] = tx2 * T[4] - T[3];
}

__device__ __forceinline__ float clampx(float v) {
    return fminf(fmaxf(v * 0.125f, -1.f + 1e-6f), 1.f - 1e-6f);
}

__device__ __forceinline__ float wave_sum(float x) {
#pragma unroll
    for (int m = 32; m >= 1; m >>= 1) x += __shfl_xor(x, m, 64);
    return x;
}

// ---------------------------------------------------------------------------
// Fused split of x (2048 blocks) and Win (3072 blocks): fp16 2-level.
// ---------------------------------------------------------------------------
__global__ __launch_bounds__(256) void k_splitall(
    const float* __restrict__ x, const float* __restrict__ Win,
    unsigned short* __restrict__ Xh, unsigned short* __restrict__ Xm,
    unsigned short* __restrict__ Wh, unsigned short* __restrict__ Wm)
{
    const float* in; unsigned short *h, *m; int i;
    if (blockIdx.x < 2048) {
        in = x; h = Xh; m = Xm;
        i = blockIdx.x * 256 + threadIdx.x;
    } else {
        in = Win; h = Wh; m = Wm;
        i = (blockIdx.x - 2048) * 256 + threadIdx.x;
    }
    split2x4(((const float4*)in)[i], h, m, i);
}

// ---------------------------------------------------------------------------
// fp16 scaled-residual MFMA GEMM, double-buffered LDS, ONE barrier per K-iter.
// C[m,n] = sum_k A[m,k]*B[n,k]; A = Ah + Am/2048, B likewise:
//   acc1 += Ah*Bh ; acc2 += Ah*Bm + Am*Bh ; C = acc1 + acc2/2048.
// Block tile TM x TN, BK=32, 256 threads = 4 waves (2x2), wave tile
// (TM/2)x(TN/2) as MTxNT grid of 16x16 (MFMA 16x16x32_f16).
//
// LDS layout (R2/R4-proven, 0 conflicts): row-major, 64 B per row (4 segs of
// 16 B); slot s of row r holds global k-segment s ^ ((r>>1)&3). Staging call
// = 16 rows x 4 segs = 1 KB: lane L covers row g*16+(L>>2), slot L&3 ->
// global 64 B contiguous per row (good coalescing); frag ds_read_b128 at
// slot q^((r>>1)&3) -> 2 lanes/bank (free).
// Double-buffer: iter it computes from buf[it&1] while staging k0+32 into
// buf[~it&1]; single __syncthreads at iter end (its vmcnt drain = the
// prefetch completion wait).
// ---------------------------------------------------------------------------
template<int TM, int TN>
__global__ __launch_bounds__(256, 2) void gemm_db(
    const unsigned short* __restrict__ Ah, const unsigned short* __restrict__ Am,
    const unsigned short* __restrict__ Bh, const unsigned short* __restrict__ Bm,
    float* __restrict__ C, int M, int N, int K)
{
    constexpr int MT = TM / 32;          // 16-row tiles per wave
    constexpr int NT = TN / 32;          // 16-col tiles per wave
    constexpr int ABYTES = TM * 64;      // one A split tile
    constexpr int BBYTES = TN * 64;      // one B split tile
    constexpr int BUF = 2 * ABYTES + 2 * BBYTES;
    constexpr int NC = (2 * TM + 2 * TN) / 16;  // 1 KB staging calls per iter
    constexpr int PW = NC / 4;                  // calls per wave
    __shared__ unsigned char lds[2 * BUF];

    const int tid = threadIdx.x;
    const int w = tid >> 6, lane = tid & 63;
    const int m0 = blockIdx.y * TM, n0 = blockIdx.x * TN;

    // ---- staging call table (uniform per wave; lane part in global addr) ----
    const unsigned short* srcp[PW];
    int goff[PW];   // element offset: (tile_row)*K + gseg*8
    int loff[PW];   // wave-uniform LDS byte base (+ lane*16 by hardware)
    {
        const int lrow4 = lane >> 2, spos = lane & 3;
#pragma unroll
        for (int j = 0; j < PW; j++) {
            const int id = w * PW + j;
            if (id < 2 * (TM / 16)) {
                const int split = id / (TM / 16), g = id % (TM / 16);
                const int row = g * 16 + lrow4;
                const int gseg = spos ^ ((row >> 1) & 3);
                srcp[j] = split ? Am : Ah;
                goff[j] = (m0 + row) * K + gseg * 8;
                loff[j] = split * ABYTES + g * 1024;
            } else {
                const int id2 = id - 2 * (TM / 16);
                const int split = id2 / (TN / 16), g = id2 % (TN / 16);
                const int row = g * 16 + lrow4;
                const int gseg = spos ^ ((row >> 1) & 3);
                srcp[j] = split ? Bm : Bh;
                goff[j] = (n0 + row) * K + gseg * 8;
                loff[j] = 2 * ABYTES + split * BBYTES + g * 1024;
            }
        }
    }

    // ---- fragment read offsets ----
    const int wm = w & 1, wn = w >> 1;
    const int l16 = lane & 15, q = lane >> 4;
    int aoff[MT], boff[NT];
#pragma unroll
    for (int mt = 0; mt < MT; mt++) {
        const int r = wm * (TM / 2) + mt * 16 + l16;
        aoff[mt] = r * 64 + ((q ^ ((r >> 1) & 3)) * 16);
    }
#pragma unroll
    for (int nt = 0; nt < NT; nt++) {
        const int r = wn * (TN / 2) + nt * 16 + l16;
        boff[nt] = 2 * ABYTES + r * 64 + ((q ^ ((r >> 1) & 3)) * 16);
    }

    floatx4 acc1[MT][NT] = {};
    floatx4 acc2[MT][NT] = {};

    // prologue: stage buf0 @ k=0
#pragma unroll
    for (int j = 0; j < PW; j++)
        cp16(srcp[j] + goff[j], &lds[loff[j]]);
    __syncthreads();

    for (int k0 = 0; k0 < K; k0 += 32) {
        const int cur = (k0 >> 5) & 1;
        // prefetch next slab into the other buffer (completes at the barrier)
        if (k0 + 32 < K) {
            const int nb = (cur ^ 1) * BUF;
#pragma unroll
            for (int j = 0; j < PW; j++)
                cp16(srcp[j] + goff[j] + k0 + 32, &lds[nb + loff[j]]);
        }
        const unsigned char* base = &lds[cur * BUF];
        half8 fbh[NT], fbm[NT];
#pragma unroll
        for (int nt = 0; nt < NT; nt++) {
            fbh[nt] = *(const half8*)(base + boff[nt]);
            fbm[nt] = *(const half8*)(base + BBYTES + boff[nt]);
        }
#pragma unroll
        for (int mt = 0; mt < MT; mt++) {
            half8 fah = *(const half8*)(base + aoff[mt]);
            half8 fam = *(const half8*)(base + ABYTES + aoff[mt]);
#pragma unroll
            for (int nt = 0; nt < NT; nt++) {
                acc1[mt][nt] = __builtin_amdgcn_mfma_f32_16x16x32_f16(
                    fah, fbh[nt], acc1[mt][nt], 0, 0, 0);
                acc2[mt][nt] = __builtin_amdgcn_mfma_f32_16x16x32_f16(
                    fah, fbm[nt], acc2[mt][nt], 0, 0, 0);
                acc2[mt][nt] = __builtin_amdgcn_mfma_f32_16x16x32_f16(
                    fam, fbh[nt], acc2[mt][nt], 0, 0, 0);
            }
        }
        __syncthreads();   // drains prefetch vmcnt + guards buf reuse
    }

    // epilogue: C/D layout col=lane&15, row=quad*4+reg
#pragma unroll
    for (int mt = 0; mt < MT; mt++) {
        const int row0 = m0 + wm * (TM / 2) + mt * 16 + q * 4;
#pragma unroll
        for (int nt = 0; nt < NT; nt++) {
            const int col = n0 + wn * (TN / 2) + nt * 16 + l16;
#pragma unroll
            for (int r = 0; r < 4; r++)
                C[(size_t)(row0 + r) * N + col] = acc1[mt][nt][r] + acc2[mt][nt][r] * RINV;
        }
    }
}

// ---------------------------------------------------------------------------
// Attention. qkv layout: [b*S+s][3072], q at h*64+d, k at +1024, v at +2048
// Fused mid kernel: [0,1024) Wout split | [1024,9216) per-position sums |
// [9216,9728) kv chunk totals.
// ---------------------------------------------------------------------------
__global__ __launch_bounds__(256) void k_mid(
    const float* __restrict__ Wout,
    unsigned short* __restrict__ Wouth, unsigned short* __restrict__ Woutm,
    const float* __restrict__ qkv,
    float* __restrict__ SQB, float* __restrict__ SK, float* __restrict__ KVC)
{
    const int blk = blockIdx.x;
    if (blk < 1024) {
        int i = blk * 256 + threadIdx.x;
        split2x4(((const float4*)Wout)[i], Wouth, Woutm, i);
        return;
    }
    if (blk < 9216) {
        const int lane = threadIdx.x & 63;
        const int pos  = (blk - 1024) * 4 + (threadIdx.x >> 6);
        const int bh = pos >> 10, s = pos & 1023;
        const int b = bh >> 4, h = bh & 15;
        const float* base = qkv + (size_t)(b * SEQ + s) * E3D + h * DHEAD + lane;
        float xq = clampx(base[0]);
        float xk = clampx(base[1024]);
        float Tq[6], Tk[6];
        cheb5(xq, Tq); cheb5(xk, Tk);
        const float BETA[5] = {BETA1, BETA2, BETA3, BETA4, BETA5};
#pragma unroll
        for (int p = 1; p <= 5; p++) {
            float sq = wave_sum(Tq[p]);
            float sk = wave_sum(Tk[p]);
            if (lane == 0) {
                SQB[(size_t)pos * 5 + p - 1] = sq * BETA[p - 1];
                SK[(size_t)pos * 5 + p - 1]  = sk;
            }
        }
        return;
    }
    {
        const int lane = threadIdx.x & 63;
        const int cid = (blk - 9216) * 4 + (threadIdx.x >> 6);
        const int bh = cid >> 6, chunk = cid & 63;
        const int b = bh >> 4, h = bh & 15;
        const float* kb = qkv + (size_t)(b * SEQ + chunk * CHUNK) * E3D + 1024 + h * DHEAD + lane;
        float kv[5] = {0.f, 0.f, 0.f, 0.f, 0.f};
#pragma unroll
        for (int i = 0; i < CHUNK; i++) {
            const float* row = kb + (size_t)i * E3D;
            float xk = clampx(row[0]);
            float v = row[1024];
            float T[6]; cheb5(xk, T);
#pragma unroll
            for (int p = 1; p <= 5; p++) kv[p - 1] += T[p] * v;
        }
#pragma unroll
        for (int p = 0; p < 5; p++) KVC[((size_t)cid * 5 + p) * 64 + lane] = kv[p];
    }
}

// Fused prefixes: (A) exclusive prefix over chunks of KVC in place (register
// preload -> independent loads); (B) SK chunk sums + exclusive prefix -> SKP.
__global__ __launch_bounds__(320) void k_prefix(float* __restrict__ KVC,
                                                const float* __restrict__ SK,
                                                float* __restrict__ SKP)
{
    __shared__ float csum[NCHUNK * 5];
    const int bh = blockIdx.x;
    const int t = threadIdx.x;   // 0..319, component = p*64+d
    float v[NCHUNK];
    const size_t base = (size_t)bh * NCHUNK * 320 + t;
#pragma unroll
    for (int c = 0; c < NCHUNK; c++) v[c] = KVC[base + (size_t)c * 320];
    float run = 0.f;
#pragma unroll
    for (int c = 0; c < NCHUNK; c++) {
        KVC[base + (size_t)c * 320] = run;
        run += v[c];
    }
    {
        const int chunk = t / 5, p = t % 5;
        const float* sb = SK + ((size_t)bh * SEQ + chunk * CHUNK) * 5 + p;
        float s = 0.f;
#pragma unroll
        for (int i = 0; i < CHUNK; i++) s += sb[i * 5];
        csum[chunk * 5 + p] = s;
    }
    __syncthreads();
    if (t < 5) {
        float run2 = 0.f;
        for (int c = 0; c < NCHUNK; c++) {
            SKP[((size_t)bh * NCHUNK + c) * 5 + t] = run2;
            run2 += csum[c * 5 + t];
        }
    }
}

// Fused den + output. One wave per chunk (4 waves/block). Lane = d.
// Writes out_h directly as fp16 2-level split (GEMM2 A operand).
__global__ __launch_bounds__(256) void k_out(const float* __restrict__ qkv,
                                             const float* __restrict__ KVC,
                                             const float* __restrict__ SK,
                                             const float* __restrict__ SKP,
                                             const float* __restrict__ SQB,
                                             unsigned short* __restrict__ OH,
                                             unsigned short* __restrict__ OM)
{
    const int lane = threadIdx.x & 63;
    const int cid = blockIdx.x * 4 + (threadIdx.x >> 6);
    const int bh = cid >> 6, chunk = cid & 63;
    const int b = bh >> 4, h = bh & 15;
    const float BETA[5] = {BETA1, BETA2, BETA3, BETA4, BETA5};

    const int li = lane & 15;
    const int pos = bh * SEQ + chunk * CHUNK + li;
    float den_r = 0.f;
#pragma unroll
    for (int p = 0; p < 5; p++) {
        float v = SK[(size_t)pos * 5 + p];
#pragma unroll
        for (int off = 1; off < 16; off <<= 1) {
            float n = __shfl_up(v, off, 64);
            if (li >= off) v += n;
        }
        den_r += SQB[(size_t)pos * 5 + p] * (SKP[((size_t)bh * NCHUNK + chunk) * 5 + p] + v);
    }

    float kv[5];
#pragma unroll
    for (int p = 0; p < 5; p++) kv[p] = KVC[((size_t)cid * 5 + p) * 64 + lane];

    const float* qb = qkv + (size_t)(b * SEQ + chunk * CHUNK) * E3D + h * DHEAD + lane;
    size_t obase = (size_t)(b * SEQ + chunk * CHUNK) * DMODEL + h * DHEAD + lane;
#pragma unroll
    for (int i = 0; i < CHUNK; i++) {
        const float* row = qb + (size_t)i * E3D;
        float xq = clampx(row[0]);
        float xk = clampx(row[1024]);
        float v = row[2048];
        float Tk_[6]; cheb5(xk, Tk_);
#pragma unroll
        for (int p = 1; p <= 5; p++) kv[p - 1] += Tk_[p] * v;
        float Tq_[6]; cheb5(xq, Tq_);
        float num = 0.f;
#pragma unroll
        for (int p = 1; p <= 5; p++) num += BETA[p - 1] * Tq_[p] * kv[p - 1];
        float d = __shfl(den_r, i, 64);
        float val = num / (d + 1e-7f);
        unsigned short hh, mm;
        split2(val, &hh, &mm);
        size_t oi = obase + (size_t)i * DMODEL;
        OH[oi] = hh; OM[oi] = mm;
    }
}

// ---------------------------------------------------------------------------

extern "C" void kernel_launch(void* const* d_in, const int* in_sizes, int n_in,
                              void* d_out, int out_size, void* d_ws, size_t ws_size,
                              hipStream_t stream)
{
    const float* x    = (const float*)d_in[0];  // (2,1024,1024)
    const float* Win  = (const float*)d_in[1];  // (3072,1024)
    const float* Wout = (const float*)d_in[2];  // (1024,1024)
    float* out = (float*)d_out;                 // (2,1024,1024)
    char* ws = (char*)d_ws;

    // workspace layout (byte offsets)
    float* QKV = (float*)(ws + 0);                              // 25,165,824 B
    unsigned short* Xh   = (unsigned short*)(ws + 25165824);    //  4,194,304 each
    unsigned short* Xm   = (unsigned short*)(ws + 29360128);
    unsigned short* Winh = (unsigned short*)(ws + 33554432);    //  6,291,456 each
    unsigned short* Winm = (unsigned short*)(ws + 39845888);    // end 46,137,344
    // After GEMM1, X/Win splits die -> reuse regions:
    float* SQB = (float*)(ws + 25165824);   // 655,360
    float* SK  = (float*)(ws + 25821184);   // 655,360
    float* SKP = (float*)(ws + 26476544);   //  40,960
    float* KVC = (float*)(ws + 26517504);   // 2,621,440 (end 29,138,944)
    unsigned short* OHh   = (unsigned short*)(ws + 33554432);   // 4,194,304 each
    unsigned short* OHm   = (unsigned short*)(ws + 37748736);
    unsigned short* Wouth = (unsigned short*)(ws + 41943040);   // 2,097,152 each
    unsigned short* Woutm = (unsigned short*)(ws + 44040192);   // end 46,137,344

    // split x + Win (one launch)
    k_splitall<<<5120, 256, 0, stream>>>(x, Win, Xh, Xm, Winh, Winm);

    // 1) QKV projection (M=2048, N=3072, K=1024): 128x96 tiles -> 512 blocks (2/CU)
    gemm_db<128, 96><<<dim3(32, 16), 256, 0, stream>>>(Xh, Xm, Winh, Winm,
                                                       QKV, BATCH * SEQ, E3D, DMODEL);

    // 2) Wout split + per-position sums + kv chunk totals (one launch)
    k_mid<<<9728, 256, 0, stream>>>(Wout, Wouth, Woutm, QKV, SQB, SK, KVC);

    // 3) prefixes
    k_prefix<<<BATCH * NHEADS, 320, 0, stream>>>(KVC, SK, SKP);

    // 4) den + output (writes out_h as fp16 split)
    k_out<<<512, 256, 0, stream>>>(QKV, KVC, SK, SKP, SQB, OHh, OHm);

    // 5) output projection (M=2048, N=1024, K=1024): 64x64 tiles -> 512 blocks (2/CU)
    gemm_db<64, 64><<<dim3(16, 32), 256, 0, stream>>>(OHh, OHm, Wouth, Woutm,
                                                      out, BATCH * SEQ, DMODEL, DMODEL);
}